// Round 18
// baseline (121.076 us; speedup 1.0000x reference)
//
#include <hip/hip_runtime.h>
#include <hip/hip_bf16.h>

typedef __attribute__((ext_vector_type(8))) short short8;
typedef __attribute__((ext_vector_type(4))) short short4v;
typedef __attribute__((ext_vector_type(4))) float f32x4;
typedef __attribute__((ext_vector_type(16))) float f32x16;
typedef __attribute__((ext_vector_type(4))) unsigned uint4v;
typedef __attribute__((ext_vector_type(2))) unsigned uint2v;

static constexpr int BATCH = 2, S = 2048, D = 1024, H = 16, DK = 64;
static constexpr int TOK = BATCH * S;     // 4096
static constexpr int NQKV = 3 * D;        // 3072
static constexpr float C2 = 0.125f * 1.44269504088896f;  // scale * log2(e)

__device__ inline unsigned short f2bf(float f) {
  unsigned int u = __builtin_bit_cast(unsigned int, f);
  unsigned int r = (u + 0x7fffu + ((u >> 16) & 1u)) >> 16;
  return (unsigned short)r;
}

__device__ inline unsigned cvt_pk_bf16(float lo, float hi) {
  unsigned r;
  asm("v_cvt_pk_bf16_f32 %0, %1, %2" : "=v"(r) : "v"(lo), "v"(hi));
  return r;
}

// swaps upper 32 lanes of arg0 with lower 32 lanes of arg1 (HW-verified builtin, T12)
__device__ inline uint2v permswap(unsigned a, unsigned b) {
  return __builtin_amdgcn_permlane32_swap(a, b, false, false);
}

__device__ inline float fexp2(float x) { return __builtin_amdgcn_exp2f(x); }

__device__ inline void gload_lds16(const void* g, void* l) {
  __builtin_amdgcn_global_load_lds((const __attribute__((address_space(1))) void*)g,
                                   (__attribute__((address_space(3))) void*)l, 16, 0, 0);
}

// ---------------- merged prep: x->bf16 (float4), W^T (64x64 float4 tiles), mask ----------------
static constexpr int NB_CVT  = (TOK * D / 4) / 256;          // 4096
static constexpr int NB_WQKV = (NQKV / 64) * (D / 64);       // 768
static constexpr int NB_WOUT = (D / 64) * (D / 64);          // 256
static constexpr int NB_MASK = TOK / 256;                    // 16

__global__ __launch_bounds__(256) void k_prep(const float* __restrict__ x,
                                              unsigned short* __restrict__ x_bf,
                                              const float* __restrict__ W_qkv,
                                              unsigned short* __restrict__ wqkv_t,
                                              const float* __restrict__ W_out,
                                              unsigned short* __restrict__ wout_t,
                                              const int* __restrict__ mask,
                                              float* __restrict__ maskadd,
                                              unsigned char* __restrict__ tileflags) {
  __shared__ float tile[64][65];
  const int bi = blockIdx.x;
  const int tid = threadIdx.x;
  if (bi < NB_CVT) {
    const int i = bi * 256 + tid;
    const float4 v = ((const float4*)x)[i];
    short4v o;
    o[0] = (short)f2bf(v.x); o[1] = (short)f2bf(v.y);
    o[2] = (short)f2bf(v.z); o[3] = (short)f2bf(v.w);
    ((short4v*)x_bf)[i] = o;
    return;
  }
  if (bi < NB_CVT + NB_WQKV + NB_WOUT) {
    const int tbi = bi - NB_CVT;
    const float* in; unsigned short* out; int C, bx, by;
    if (tbi < NB_WQKV) { in = W_qkv; out = wqkv_t; C = NQKV; bx = tbi % (NQKV / 64); by = tbi / (NQKV / 64); }
    else { const int u = tbi - NB_WQKV; in = W_out; out = wout_t; C = D; bx = u % (D / 64); by = u / (D / 64); }
    const int bc = bx * 64, br = by * 64;
    const int lrow = tid >> 4, lc4 = (tid & 15) * 4;
#pragma unroll
    for (int p = 0; p < 4; ++p) {
      const float4 v = *(const float4*)(in + (size_t)(br + p * 16 + lrow) * C + bc + lc4);
      tile[p * 16 + lrow][lc4 + 0] = v.x;
      tile[p * 16 + lrow][lc4 + 1] = v.y;
      tile[p * 16 + lrow][lc4 + 2] = v.z;
      tile[p * 16 + lrow][lc4 + 3] = v.w;
    }
    __syncthreads();
    const int c = tid >> 2, seg = (tid & 3) * 16;
    uint4v w0, w1;
#pragma unroll
    for (int j = 0; j < 4; ++j) {
      w0[j] = cvt_pk_bf16(tile[seg + 2 * j][c], tile[seg + 2 * j + 1][c]);
      w1[j] = cvt_pk_bf16(tile[seg + 8 + 2 * j][c], tile[seg + 9 + 2 * j][c]);
    }
    unsigned short* dst = out + (size_t)(bc + c) * D + br + seg;
    *(uint4v*)dst = w0;
    *(uint4v*)(dst + 8) = w1;
    return;
  }
  {
    const int j = (bi - NB_CVT - NB_WQKV - NB_WOUT) * 256 + tid;
    const int mv = mask[j];
    maskadd[j] = mv ? 0.f : -1.0e9f;
    const unsigned long long bal = __ballot(mv == 0);
    if ((tid & 63) == 0) tileflags[j >> 6] = (bal != 0ull) ? 1 : 0;
  }
}

// ---------------- QKV GEMM: 256x256 tile, BK=64, 8 waves, 8-phase counted-vmcnt ----------------
// C = x_bf[4096,1024] @ wqkv_t[3072,1024]^T + bias. Q cols scaled by C2; V cols -> vt transposed.
// LDS 128 KB: A/B x 2 dbuf x 2 halves (16 KB each, 128 rows x 128B, 8-slot XOR swizzle).
// Schedule: k even->dbuf0 (phases 0-3), k odd->dbuf1 (phases 4-7); stage dbuf1<-k1 during
// phases 0-3, dbuf0<-k0+2 during phases 4-7; vmcnt(0) only at end of phases 3 and 7.
__global__ __launch_bounds__(512, 1) void k_gemm_qkv(const unsigned short* __restrict__ A,
                                                     const unsigned short* __restrict__ Bt,
                                                     const float* __restrict__ bias,
                                                     unsigned short* __restrict__ qkv,
                                                     unsigned short* __restrict__ vt) {
  constexpr int K = D;       // 1024
  constexpr int N = NQKV;    // 3072
  __shared__ alignas(16) char As[2][2][16384];
  __shared__ alignas(16) char Bs[2][2][16384];

  const int tid = threadIdx.x;
  const int wid = tid >> 6, lane = tid & 63;
  const int lr = lane & 15, lg = lane >> 4;
  const int wave_m = wid >> 2, wave_n = wid & 3;

  const int blk = blockIdx.x;
  const int work = (blk & 7) * 24 + (blk >> 3);   // 192 = 8*24, bijective XCD chunking
  const int bx = work % 12, by = work / 12;
  const int m0 = by * 256, n0 = bx * 256;

  const int srow = lane >> 3;                  // 0..7
  const int sk = ((lane & 7) ^ srow) << 4;     // pre-swizzled source byte-in-row

  f32x4 acc[8][4] = {};

  auto stageA = [&](int d, int h, int k) {
#pragma unroll
    for (int c = 0; c < 2; ++c) {
      const int chunk = c * 8 + wid;
      const int row = chunk * 8 + srow;
      gload_lds16((const char*)(A + (size_t)(m0 + h * 128 + row) * K + k * 64) + sk,
                  &As[d][h][chunk * 1024]);
    }
  };
  auto stageB = [&](int d, int h, int k) {
#pragma unroll
    for (int c = 0; c < 2; ++c) {
      const int chunk = c * 8 + wid;
      const int row = chunk * 8 + srow;
      gload_lds16((const char*)(Bt + (size_t)(n0 + h * 128 + row) * K + k * 64) + sk,
                  &Bs[d][h][chunk * 1024]);
    }
  };

  // prologue: k=0 -> dbuf0 (first 8), k=1 -> dbuf1 (next 8)
  stageA(0, 0, 0); stageA(0, 1, 0); stageB(0, 0, 0); stageB(0, 1, 0);
  stageA(1, 0, 1); stageA(1, 1, 1); stageB(1, 0, 1); stageB(1, 1, 1);
  asm volatile("s_waitcnt vmcnt(8)" ::: "memory");   // k=0 landed; k=1 still flying
  __builtin_amdgcn_s_barrier();
  __builtin_amdgcn_sched_barrier(0);

  const int rsw = (lr & 7) << 4;
  const int nbase = (wave_n & 1) * 64;

  for (int it = 0; it < 8; ++it) {
    const int k1 = 2 * it + 1;
    const int k2 = 2 * it + 2;
#pragma unroll
    for (int p = 0; p < 8; ++p) {
      const int g = p >> 2;              // group: 0 => k0/dbuf0, 1 => k1/dbuf1
      const int mh = (p >> 1) & 1, nh = p & 1;
      const char* Ab = &As[g][wave_m][0];
      const char* Bb = &Bs[g][wave_n >> 1][0];

      // ds-load register subtile: 8 A-frags + 4 B-frags
      short8 af[4][2], bfr[2][2];
#pragma unroll
      for (int j = 0; j < 4; ++j) {
        const int row = (mh * 4 + j) * 16 + lr;
#pragma unroll
        for (int ks = 0; ks < 2; ++ks)
          af[j][ks] = *(const short8*)(Ab + row * 128 + ((ks * 64 + lg * 16) ^ rsw));
      }
#pragma unroll
      for (int j2 = 0; j2 < 2; ++j2) {
        const int row = nbase + (nh * 2 + j2) * 16 + lr;
#pragma unroll
        for (int ks = 0; ks < 2; ++ks)
          bfr[j2][ks] = *(const short8*)(Bb + row * 128 + ((ks * 64 + lg * 16) ^ rsw));
      }

      // stage one half-tile (2 gloads)
      if (g == 0) {
        if (it > 0) {                    // it==0: prologue already staged k1
          if (p == 0) stageA(1, 0, k1);
          else if (p == 1) stageA(1, 1, k1);
          else if (p == 2) stageB(1, 0, k1);
          else stageB(1, 1, k1);
        }
      } else {
        if (it < 7) {
          if (p == 4) stageA(0, 0, k2);
          else if (p == 5) stageA(0, 1, k2);
          else if (p == 6) stageB(0, 0, k2);
          else stageB(0, 1, k2);
        }
      }
      if (p == 3 || p == 7) asm volatile("s_waitcnt vmcnt(0)" ::: "memory");
      __builtin_amdgcn_s_barrier();
      __builtin_amdgcn_sched_barrier(0);

      __builtin_amdgcn_s_setprio(1);
#pragma unroll
      for (int j = 0; j < 4; ++j)
#pragma unroll
        for (int j2 = 0; j2 < 2; ++j2)
#pragma unroll
          for (int ks = 0; ks < 2; ++ks)
            acc[mh * 4 + j][nh * 2 + j2] = __builtin_amdgcn_mfma_f32_16x16x32_bf16(
                af[j][ks], bfr[j2][ks], acc[mh * 4 + j][nh * 2 + j2], 0, 0, 0);
      __builtin_amdgcn_s_setprio(0);
      __builtin_amdgcn_s_barrier();
      __builtin_amdgcn_sched_barrier(0);
    }
  }

  // epilogue: Q cols scaled, K cols plain, V cols transposed into vt
#pragma unroll
  for (int nf = 0; nf < 4; ++nf) {
    const int n = n0 + wave_n * 64 + nf * 16 + lr;
    const float bv = bias[n];
    if (n < 2 * D) {
      const float scl = (n < D) ? C2 : 1.0f;
#pragma unroll
      for (int mf = 0; mf < 8; ++mf)
#pragma unroll
        for (int r = 0; r < 4; ++r) {
          const int m = m0 + wave_m * 128 + mf * 16 + lg * 4 + r;
          qkv[(size_t)m * N + n] = f2bf((acc[mf][nf][r] + bv) * scl);
        }
    } else {
      const int dd = n - 2 * D;
      const int hh = dd >> 6, dk = dd & 63;
#pragma unroll
      for (int mf = 0; mf < 8; ++mf) {
        const int mbase = m0 + wave_m * 128 + mf * 16 + lg * 4;
        const int bb = mbase >> 11;
        const int ss = mbase & (S - 1);
        uint2 w;
        w.x = cvt_pk_bf16(acc[mf][nf][0] + bv, acc[mf][nf][1] + bv);
        w.y = cvt_pk_bf16(acc[mf][nf][2] + bv, acc[mf][nf][3] + bv);
        *(uint2*)(vt + ((size_t)((bb * H + hh) * DK + dk)) * S + ss) = w;
      }
    }
  }
}

// ---------------- out GEMM: A[M,K] bf16 @ Bt[N,K]^T + bias -> C[M,N] f32 (128x128) ----------------
__global__ __launch_bounds__(256, 3) void k_gemm_out(const unsigned short* __restrict__ A,
                                                     const unsigned short* __restrict__ Bt,
                                                     const float* __restrict__ bias,
                                                     float* __restrict__ Cout,
                                                     int M, int N, int K) {
  __shared__ alignas(16) unsigned short As[128 * 64];
  __shared__ alignas(16) unsigned short Bs[128 * 64];
  const int tid = threadIdx.x;
  const int wid = tid >> 6, lane = tid & 63;
  const int lr = lane & 15, lg = lane >> 4;
  const int nbx = N >> 7;
  const int bx = blockIdx.x % nbx, by = blockIdx.x / nbx;
  const int m0 = by << 7, n0 = bx << 7;
  const int wm = (wid >> 1) << 6, wn = (wid & 1) << 6;

  f32x4 acc[4][4] = {};

  const int sk = ((lane & 7) ^ (lane >> 3)) << 4;
  const int srow = lane >> 3;

  const int ktc = K >> 6;
  for (int kt = 0; kt < ktc; ++kt) {
    const int k0 = kt << 6;
    __syncthreads();
#pragma unroll
    for (int c = 0; c < 4; ++c) {
      const int chunk = c * 4 + wid;
      const int mrow = chunk * 8 + srow;
      const char* ga = (const char*)(A + (size_t)(m0 + mrow) * K + k0) + sk;
      gload_lds16(ga, (char*)As + chunk * 1024);
      const char* gb = (const char*)(Bt + (size_t)(n0 + mrow) * K + k0) + sk;
      gload_lds16(gb, (char*)Bs + chunk * 1024);
    }
    __syncthreads();
#pragma unroll
    for (int ks = 0; ks < 2; ++ks) {
      const int kb = ks * 64 + lg * 16;
      const int swz = (lr & 7) << 4;
      short8 af[4], bfr[4];
#pragma unroll
      for (int mf = 0; mf < 4; ++mf) {
        const int m = wm + mf * 16 + lr;
        af[mf] = *(const short8*)((const char*)As + m * 128 + (kb ^ swz));
      }
#pragma unroll
      for (int nf = 0; nf < 4; ++nf) {
        const int n = wn + nf * 16 + lr;
        bfr[nf] = *(const short8*)((const char*)Bs + n * 128 + (kb ^ swz));
      }
#pragma unroll
      for (int mf = 0; mf < 4; ++mf)
#pragma unroll
        for (int nf = 0; nf < 4; ++nf)
          acc[mf][nf] = __builtin_amdgcn_mfma_f32_16x16x32_bf16(af[mf], bfr[nf], acc[mf][nf], 0, 0, 0);
    }
  }
#pragma unroll
  for (int nf = 0; nf < 4; ++nf) {
    const int n = n0 + wn + nf * 16 + lr;
    const float bv = bias[n];
#pragma unroll
    for (int mf = 0; mf < 4; ++mf)
#pragma unroll
      for (int r = 0; r < 4; ++r) {
        const int m = m0 + wm + mf * 16 + lg * 4 + r;
        Cout[(size_t)m * N + n] = acc[mf][nf][r] + bv;
      }
  }
}

// ---------------- flash attention (v13): KVBLK=128, in-register P ----------------
__global__ __launch_bounds__(256, 2) void k_attn(const unsigned short* __restrict__ qkv,
                                                 const unsigned short* __restrict__ vt,
                                                 const float* __restrict__ maskadd,
                                                 const unsigned char* __restrict__ tileflags,
                                                 unsigned short* __restrict__ attn) {
  __shared__ alignas(16) char Ks[2][16384];  // [128 keys][128B], 8-slot XOR
  __shared__ alignas(16) char Vs[2][16384];  // [64 d][256B], 16-slot XOR

  constexpr int NT = S / 128;  // 16 tiles

  const int blk = blockIdx.x;
  const int work = (blk & 7) * 64 + (blk >> 3);   // XCD-chunked swizzle (512=8*64)
  const int qt = work & 15;
  const int bh = work >> 4;
  const int b = bh >> 4, h = bh & 15;
  const int tid = threadIdx.x;
  const int wid = tid >> 6, lane = tid & 63;
  const int l5 = lane & 31, hw = lane >> 5;
  const int q0 = qt * 128 + wid * 32;
  const int q = q0 + l5;                 // this lane's q row

  const unsigned char* bflags = tileflags + b * (S / 64);

  const unsigned short* qrow = qkv + (size_t)(b * S + q) * NQKV + h * DK;
  short8 qf[4];
#pragma unroll
  for (int ks = 0; ks < 4; ++ks)
    qf[ks] = *(const short8*)(qrow + ks * 16 + hw * 8);

  const unsigned short* kg0 = qkv + ((size_t)b * S * NQKV + D + h * DK);
  const unsigned short* vg0 = vt + (size_t)bh * DK * S;
  const int srow8 = lane >> 3;
  const int skk = ((lane & 7) ^ srow8) << 4;
  const int vrow4 = lane >> 4;

  auto stage = [&](int buf, int kt) {
    const int kbase = kt * 128;
#pragma unroll
    for (int i = 0; i < 4; ++i) {
      const int ck = wid + i * 4;
      const int krow = ck * 8 + srow8;
      gload_lds16((const char*)(kg0 + (size_t)(kbase + krow) * NQKV) + skk,
                  Ks[buf] + ck * 1024);
      const int cv = wid + i * 4;
      const int vr = cv * 4 + vrow4;
      const int ss = (lane & 15) ^ (vr & 15);
      gload_lds16((const char*)(vg0 + (size_t)vr * S + kbase + ss * 8),
                  Vs[buf] + cv * 1024);
    }
  };

  f32x16 o[2] = {};
  float lpart = 0.f;

  const int rswz8 = (l5 & 7) << 4;
  const int rswz16 = (l5 & 15) << 4;

  stage(0, 0);

  int cur = 0;
  for (int kt = 0; kt < NT; ++kt) {
    asm volatile("s_waitcnt vmcnt(0)" ::: "memory");
    __builtin_amdgcn_s_barrier();
    __builtin_amdgcn_sched_barrier(0);
    if (kt + 1 < NT) stage(cur ^ 1, kt + 1);

    const int kbase = kt * 128;

    f32x16 sc[4];
    __builtin_amdgcn_s_setprio(1);
#pragma unroll
    for (int kh = 0; kh < 4; ++kh) {
      f32x16 t2 = {};
#pragma unroll
      for (int ks = 0; ks < 4; ++ks) {
        const short8 kf = *(const short8*)(Ks[cur] + (kh * 32 + l5) * 128 +
                                           ((ks * 32 + hw * 16) ^ rswz8));
        t2 = __builtin_amdgcn_mfma_f32_32x32x16_bf16(kf, qf[ks], t2, 0, 0, 0);
      }
      sc[kh] = t2;
    }
    __builtin_amdgcn_s_setprio(0);

    short8 vf[2][8];
#pragma unroll
    for (int dh = 0; dh < 2; ++dh)
#pragma unroll
      for (int s = 0; s < 8; ++s)
        vf[dh][s] = *(const short8*)(Vs[cur] + (dh * 32 + l5) * 256 +
                                     ((s * 32 + hw * 16) ^ rswz16));

    if (bflags[2 * kt] | bflags[2 * kt + 1]) {
#pragma unroll
      for (int kh = 0; kh < 4; ++kh)
#pragma unroll
        for (int m = 0; m < 4; ++m) {
          const f32x4 a4 = *(const f32x4*)(maskadd + b * S + kbase + kh * 32 + m * 8 + hw * 4);
#pragma unroll
          for (int r = 0; r < 4; ++r)
            sc[kh][m * 4 + r] += a4[r];
        }
    }

    float ps = 0.f;
#pragma unroll
    for (int kh = 0; kh < 4; ++kh) {
#pragma unroll
      for (int r = 0; r < 16; ++r)
        sc[kh][r] = fexp2(sc[kh][r]);
#pragma unroll
      for (int m = 0; m < 4; ++m)
        ps += (sc[kh][4 * m] + sc[kh][4 * m + 1]) + (sc[kh][4 * m + 2] + sc[kh][4 * m + 3]);

      const unsigned c00 = cvt_pk_bf16(sc[kh][0], sc[kh][1]);
      const unsigned c01 = cvt_pk_bf16(sc[kh][2], sc[kh][3]);
      const unsigned c10 = cvt_pk_bf16(sc[kh][4], sc[kh][5]);
      const unsigned c11 = cvt_pk_bf16(sc[kh][6], sc[kh][7]);
      const unsigned c20 = cvt_pk_bf16(sc[kh][8], sc[kh][9]);
      const unsigned c21 = cvt_pk_bf16(sc[kh][10], sc[kh][11]);
      const unsigned c30 = cvt_pk_bf16(sc[kh][12], sc[kh][13]);
      const unsigned c31 = cvt_pk_bf16(sc[kh][14], sc[kh][15]);
      const uint2v r0 = permswap(c00, c10);
      const uint2v r1 = permswap(c01, c11);
      const uint2v r2 = permswap(c20, c30);
      const uint2v r3 = permswap(c21, c31);
      uint4v p0, p1;
      p0[0] = r0[0]; p0[2] = r0[1]; p0[1] = r1[0]; p0[3] = r1[1];
      p1[0] = r2[0]; p1[2] = r2[1]; p1[1] = r3[0]; p1[3] = r3[1];
      const short8 pb0 = __builtin_bit_cast(short8, p0);
      const short8 pb1 = __builtin_bit_cast(short8, p1);

      __builtin_amdgcn_s_setprio(1);
#pragma unroll
      for (int dh = 0; dh < 2; ++dh) {
        o[dh] = __builtin_amdgcn_mfma_f32_32x32x16_bf16(vf[dh][2 * kh], pb0, o[dh], 0, 0, 0);
        o[dh] = __builtin_amdgcn_mfma_f32_32x32x16_bf16(vf[dh][2 * kh + 1], pb1, o[dh], 0, 0, 0);
      }
      __builtin_amdgcn_s_setprio(0);
    }
    lpart += ps;

    cur ^= 1;
  }

  const float ls = lpart + __shfl_xor(lpart, 32);
  const float inv = 1.0f / ls;
  unsigned short* orow = attn + (size_t)(b * S + q) * D + h * DK;
#pragma unroll
  for (int dh = 0; dh < 2; ++dh)
#pragma unroll
    for (int m = 0; m < 4; ++m) {
      const int d = dh * 32 + m * 8 + hw * 4;
      uint2 w;
      w.x = cvt_pk_bf16(o[dh][4 * m + 0] * inv, o[dh][4 * m + 1] * inv);
      w.y = cvt_pk_bf16(o[dh][4 * m + 2] * inv, o[dh][4 * m + 3] * inv);
      *(uint2*)(orow + d) = w;
    }
}

extern "C" void kernel_launch(void* const* d_in, const int* in_sizes, int n_in,
                              void* d_out, int out_size, void* d_ws, size_t ws_size,
                              hipStream_t stream) {
  const float* x = (const float*)d_in[0];
  const int* mask = (const int*)d_in[1];
  const float* W_qkv = (const float*)d_in[2];
  const float* b_qkv = (const float*)d_in[3];
  const float* W_out = (const float*)d_in[4];
  const float* b_out = (const float*)d_in[5];
  float* out = (float*)d_out;

  char* ws = (char*)d_ws;
  unsigned short* x_bf   = (unsigned short*)(ws);                          //  0..8 MB
  unsigned short* wqkv_t = (unsigned short*)(ws + (size_t)(8 << 20));      //  8..14 MB
  unsigned short* wout_t = (unsigned short*)(ws + (size_t)(14 << 20));     // 14..16 MB
  unsigned short* qkv    = (unsigned short*)(ws + (size_t)(16 << 20));     // 16..40 MB
  unsigned short* vtr    = (unsigned short*)(ws + (size_t)(40 << 20));     // 40..48 MB
  unsigned short* attn   = (unsigned short*)(ws + (size_t)(48 << 20));     // 48..56 MB
  float*          madd   = (float*)(ws + (size_t)(56 << 20));              // 16 KB
  unsigned char*  tflags = (unsigned char*)(ws + (size_t)(56 << 20) + 16384);  // 64 B

  k_prep<<<NB_CVT + NB_WQKV + NB_WOUT + NB_MASK, 256, 0, stream>>>(
      x, x_bf, W_qkv, wqkv_t, W_out, wout_t, mask, madd, tflags);
  k_gemm_qkv<<<(TOK / 256) * (NQKV / 256), 512, 0, stream>>>(x_bf, wqkv_t, b_qkv, qkv, vtr);
  k_attn<<<BATCH * H * (S / 128), 256, 0, stream>>>(qkv, vtr, madd, tflags, attn);
  k_gemm_out<<<(TOK / 128) * (D / 128), 256, 0, stream>>>(attn, wout_t, b_out, out, TOK, D, D);
}

// Round 19
// 102.777 us; speedup vs baseline: 1.1780x; 1.1780x over previous
//
#include <hip/hip_runtime.h>
#include <hip/hip_bf16.h>

typedef __attribute__((ext_vector_type(8))) short short8;
typedef __attribute__((ext_vector_type(4))) short short4v;
typedef __attribute__((ext_vector_type(4))) float f32x4;
typedef __attribute__((ext_vector_type(16))) float f32x16;
typedef __attribute__((ext_vector_type(4))) unsigned uint4v;
typedef __attribute__((ext_vector_type(2))) unsigned uint2v;

static constexpr int BATCH = 2, S = 2048, D = 1024, H = 16, DK = 64;
static constexpr int TOK = BATCH * S;     // 4096
static constexpr int NQKV = 3 * D;        // 3072
static constexpr float C2 = 0.125f * 1.44269504088896f;  // scale * log2(e)

__device__ inline unsigned short f2bf(float f) {
  unsigned int u = __builtin_bit_cast(unsigned int, f);
  unsigned int r = (u + 0x7fffu + ((u >> 16) & 1u)) >> 16;
  return (unsigned short)r;
}

__device__ inline unsigned cvt_pk_bf16(float lo, float hi) {
  unsigned r;
  asm("v_cvt_pk_bf16_f32 %0, %1, %2" : "=v"(r) : "v"(lo), "v"(hi));
  return r;
}

// swaps upper 32 lanes of arg0 with lower 32 lanes of arg1 (HW-verified builtin, T12)
__device__ inline uint2v permswap(unsigned a, unsigned b) {
  return __builtin_amdgcn_permlane32_swap(a, b, false, false);
}

__device__ inline float fexp2(float x) { return __builtin_amdgcn_exp2f(x); }

__device__ inline void gload_lds16(const void* g, void* l) {
  __builtin_amdgcn_global_load_lds((const __attribute__((address_space(1))) void*)g,
                                   (__attribute__((address_space(3))) void*)l, 16, 0, 0);
}

// ---------------- merged prep: x->bf16 (float4), W^T (64x64 float4 tiles), mask ----------------
static constexpr int NB_CVT  = (TOK * D / 4) / 256;          // 4096
static constexpr int NB_WQKV = (NQKV / 64) * (D / 64);       // 768
static constexpr int NB_WOUT = (D / 64) * (D / 64);          // 256
static constexpr int NB_MASK = TOK / 256;                    // 16

__global__ __launch_bounds__(256) void k_prep(const float* __restrict__ x,
                                              unsigned short* __restrict__ x_bf,
                                              const float* __restrict__ W_qkv,
                                              unsigned short* __restrict__ wqkv_t,
                                              const float* __restrict__ W_out,
                                              unsigned short* __restrict__ wout_t,
                                              const int* __restrict__ mask,
                                              float* __restrict__ maskadd,
                                              unsigned char* __restrict__ tileflags) {
  __shared__ float tile[64][65];
  const int bi = blockIdx.x;
  const int tid = threadIdx.x;
  if (bi < NB_CVT) {
    const int i = bi * 256 + tid;
    const float4 v = ((const float4*)x)[i];
    short4v o;
    o[0] = (short)f2bf(v.x); o[1] = (short)f2bf(v.y);
    o[2] = (short)f2bf(v.z); o[3] = (short)f2bf(v.w);
    ((short4v*)x_bf)[i] = o;
    return;
  }
  if (bi < NB_CVT + NB_WQKV + NB_WOUT) {
    const int tbi = bi - NB_CVT;
    const float* in; unsigned short* out; int C, bx, by;
    if (tbi < NB_WQKV) { in = W_qkv; out = wqkv_t; C = NQKV; bx = tbi % (NQKV / 64); by = tbi / (NQKV / 64); }
    else { const int u = tbi - NB_WQKV; in = W_out; out = wout_t; C = D; bx = u % (D / 64); by = u / (D / 64); }
    const int bc = bx * 64, br = by * 64;
    const int lrow = tid >> 4, lc4 = (tid & 15) * 4;
#pragma unroll
    for (int p = 0; p < 4; ++p) {
      const float4 v = *(const float4*)(in + (size_t)(br + p * 16 + lrow) * C + bc + lc4);
      tile[p * 16 + lrow][lc4 + 0] = v.x;
      tile[p * 16 + lrow][lc4 + 1] = v.y;
      tile[p * 16 + lrow][lc4 + 2] = v.z;
      tile[p * 16 + lrow][lc4 + 3] = v.w;
    }
    __syncthreads();
    const int c = tid >> 2, seg = (tid & 3) * 16;
    uint4v w0, w1;
#pragma unroll
    for (int j = 0; j < 4; ++j) {
      w0[j] = cvt_pk_bf16(tile[seg + 2 * j][c], tile[seg + 2 * j + 1][c]);
      w1[j] = cvt_pk_bf16(tile[seg + 8 + 2 * j][c], tile[seg + 9 + 2 * j][c]);
    }
    unsigned short* dst = out + (size_t)(bc + c) * D + br + seg;
    *(uint4v*)dst = w0;
    *(uint4v*)(dst + 8) = w1;
    return;
  }
  {
    const int j = (bi - NB_CVT - NB_WQKV - NB_WOUT) * 256 + tid;
    const int mv = mask[j];
    maskadd[j] = mv ? 0.f : -1.0e9f;
    const unsigned long long bal = __ballot(mv == 0);
    if ((tid & 63) == 0) tileflags[j >> 6] = (bal != 0ull) ? 1 : 0;
  }
}

// ---------------- QKV GEMM (proven 128x128): bf16 out; Q scaled; V transposed to vt ----------------
__global__ __launch_bounds__(256, 3) void k_gemm_qkv(const unsigned short* __restrict__ A,
                                                     const unsigned short* __restrict__ Bt,
                                                     const float* __restrict__ bias,
                                                     unsigned short* __restrict__ qkv,
                                                     unsigned short* __restrict__ vt) {
  constexpr int K = D, N = NQKV, M = TOK;
  __shared__ alignas(16) unsigned short As[128 * 64];
  __shared__ alignas(16) unsigned short Bs[128 * 64];
  const int tid = threadIdx.x;
  const int wid = tid >> 6, lane = tid & 63;
  const int lr = lane & 15, lg = lane >> 4;
  const int nbx = N >> 7;
  const int bx = blockIdx.x % nbx, by = blockIdx.x / nbx;
  const int m0 = by << 7, n0 = bx << 7;
  const int wm = (wid >> 1) << 6, wn = (wid & 1) << 6;

  f32x4 acc[4][4] = {};

  const int sk = ((lane & 7) ^ (lane >> 3)) << 4;
  const int srow = lane >> 3;

  const int ktc = K >> 6;
  for (int kt = 0; kt < ktc; ++kt) {
    const int k0 = kt << 6;
    __syncthreads();
#pragma unroll
    for (int c = 0; c < 4; ++c) {
      const int chunk = c * 4 + wid;
      const int mrow = chunk * 8 + srow;
      const char* ga = (const char*)(A + (size_t)(m0 + mrow) * K + k0) + sk;
      gload_lds16(ga, (char*)As + chunk * 1024);
      const char* gb = (const char*)(Bt + (size_t)(n0 + mrow) * K + k0) + sk;
      gload_lds16(gb, (char*)Bs + chunk * 1024);
    }
    __syncthreads();
#pragma unroll
    for (int ks = 0; ks < 2; ++ks) {
      const int kb = ks * 64 + lg * 16;
      const int swz = (lr & 7) << 4;
      short8 af[4], bfr[4];
#pragma unroll
      for (int mf = 0; mf < 4; ++mf) {
        const int m = wm + mf * 16 + lr;
        af[mf] = *(const short8*)((const char*)As + m * 128 + (kb ^ swz));
      }
#pragma unroll
      for (int nf = 0; nf < 4; ++nf) {
        const int n = wn + nf * 16 + lr;
        bfr[nf] = *(const short8*)((const char*)Bs + n * 128 + (kb ^ swz));
      }
#pragma unroll
      for (int mf = 0; mf < 4; ++mf)
#pragma unroll
        for (int nf = 0; nf < 4; ++nf)
          acc[mf][nf] = __builtin_amdgcn_mfma_f32_16x16x32_bf16(af[mf], bfr[nf], acc[mf][nf], 0, 0, 0);
    }
  }
#pragma unroll
  for (int nf = 0; nf < 4; ++nf) {
    const int n = n0 + wn + nf * 16 + lr;
    const float bv = bias[n];
    if (n < 2 * D) {
      const float scl = (n < D) ? C2 : 1.0f;
#pragma unroll
      for (int mf = 0; mf < 4; ++mf)
#pragma unroll
        for (int r = 0; r < 4; ++r) {
          const int m = m0 + wm + mf * 16 + lg * 4 + r;
          qkv[(size_t)m * N + n] = f2bf((acc[mf][nf][r] + bv) * scl);
        }
    } else {
      const int dd = n - 2 * D;
      const int hh = dd >> 6, dk = dd & 63;
#pragma unroll
      for (int mf = 0; mf < 4; ++mf) {
        const int mbase = m0 + wm + mf * 16 + lg * 4;
        const int bb = mbase >> 11;
        const int ss = mbase & (S - 1);
        uint2 w;
        w.x = cvt_pk_bf16(acc[mf][nf][0] + bv, acc[mf][nf][1] + bv);
        w.y = cvt_pk_bf16(acc[mf][nf][2] + bv, acc[mf][nf][3] + bv);
        *(uint2*)(vt + ((size_t)((bb * H + hh) * DK + dk)) * S + ss) = w;
      }
    }
  }
}

// ---------------- out GEMM: BM=64 x BN=128 (grid 512 = 2 blocks/CU, 2 waves/SIMD) ----------------
// A[M,K] bf16 @ Bt[N,K]^T + bias -> C[M,N] f32. 4 waves each own 64x32 (acc[4][2]).
__global__ __launch_bounds__(256, 2) void k_gemm_out(const unsigned short* __restrict__ A,
                                                     const unsigned short* __restrict__ Bt,
                                                     const float* __restrict__ bias,
                                                     float* __restrict__ Cout,
                                                     int M, int N, int K) {
  __shared__ alignas(16) unsigned short As[64 * 64];    // 8 KB
  __shared__ alignas(16) unsigned short Bs[128 * 64];   // 16 KB
  const int tid = threadIdx.x;
  const int wid = tid >> 6, lane = tid & 63;
  const int lr = lane & 15, lg = lane >> 4;
  const int nbx = N >> 7;                               // 8
  const int blk = blockIdx.x;
  const int work = (blk & 7) * 64 + (blk >> 3);         // 512 = 8*64 bijective XCD swizzle
  const int bx = work % nbx, by = work / nbx;
  const int m0 = by << 6, n0 = bx << 7;
  const int wn = wid << 5;                              // wave n-offset (0,32,64,96)

  f32x4 acc[4][2] = {};

  const int sk = ((lane & 7) ^ (lane >> 3)) << 4;
  const int srow = lane >> 3;

  const int ktc = K >> 6;
  for (int kt = 0; kt < ktc; ++kt) {
    const int k0 = kt << 6;
    __syncthreads();
    // A: 8 chunks (64 rows), B: 16 chunks (128 rows); 6 chunk-loads per wave
#pragma unroll
    for (int i = 0; i < 2; ++i) {
      const int ca = wid + i * 4;                       // 0..7
      const int arow = ca * 8 + srow;
      gload_lds16((const char*)(A + (size_t)(m0 + arow) * K + k0) + sk, (char*)As + ca * 1024);
    }
#pragma unroll
    for (int i = 0; i < 4; ++i) {
      const int cb = wid + i * 4;                       // 0..15
      const int brow = cb * 8 + srow;
      gload_lds16((const char*)(Bt + (size_t)(n0 + brow) * K + k0) + sk, (char*)Bs + cb * 1024);
    }
    __syncthreads();
#pragma unroll
    for (int ks = 0; ks < 2; ++ks) {
      const int kb = ks * 64 + lg * 16;
      const int swz = (lr & 7) << 4;
      short8 af[4], bfr[2];
#pragma unroll
      for (int mf = 0; mf < 4; ++mf) {
        const int m = mf * 16 + lr;
        af[mf] = *(const short8*)((const char*)As + m * 128 + (kb ^ swz));
      }
#pragma unroll
      for (int nf = 0; nf < 2; ++nf) {
        const int n = wn + nf * 16 + lr;
        bfr[nf] = *(const short8*)((const char*)Bs + n * 128 + (kb ^ swz));
      }
#pragma unroll
      for (int mf = 0; mf < 4; ++mf)
#pragma unroll
        for (int nf = 0; nf < 2; ++nf)
          acc[mf][nf] = __builtin_amdgcn_mfma_f32_16x16x32_bf16(af[mf], bfr[nf], acc[mf][nf], 0, 0, 0);
    }
  }
#pragma unroll
  for (int nf = 0; nf < 2; ++nf) {
    const int n = n0 + wn + nf * 16 + lr;
    const float bv = bias[n];
#pragma unroll
    for (int mf = 0; mf < 4; ++mf)
#pragma unroll
      for (int r = 0; r < 4; ++r) {
        const int m = m0 + mf * 16 + lg * 4 + r;
        Cout[(size_t)m * N + n] = acc[mf][nf][r] + bv;
      }
  }
}

// ---------------- flash attention (v13): KVBLK=128, in-register P ----------------
__global__ __launch_bounds__(256, 2) void k_attn(const unsigned short* __restrict__ qkv,
                                                 const unsigned short* __restrict__ vt,
                                                 const float* __restrict__ maskadd,
                                                 const unsigned char* __restrict__ tileflags,
                                                 unsigned short* __restrict__ attn) {
  __shared__ alignas(16) char Ks[2][16384];  // [128 keys][128B], 8-slot XOR
  __shared__ alignas(16) char Vs[2][16384];  // [64 d][256B], 16-slot XOR

  constexpr int NT = S / 128;  // 16 tiles

  const int blk = blockIdx.x;
  const int work = (blk & 7) * 64 + (blk >> 3);   // XCD-chunked swizzle (512=8*64)
  const int qt = work & 15;
  const int bh = work >> 4;
  const int b = bh >> 4, h = bh & 15;
  const int tid = threadIdx.x;
  const int wid = tid >> 6, lane = tid & 63;
  const int l5 = lane & 31, hw = lane >> 5;
  const int q0 = qt * 128 + wid * 32;
  const int q = q0 + l5;                 // this lane's q row

  const unsigned char* bflags = tileflags + b * (S / 64);

  const unsigned short* qrow = qkv + (size_t)(b * S + q) * NQKV + h * DK;
  short8 qf[4];
#pragma unroll
  for (int ks = 0; ks < 4; ++ks)
    qf[ks] = *(const short8*)(qrow + ks * 16 + hw * 8);

  const unsigned short* kg0 = qkv + ((size_t)b * S * NQKV + D + h * DK);
  const unsigned short* vg0 = vt + (size_t)bh * DK * S;
  const int srow8 = lane >> 3;
  const int skk = ((lane & 7) ^ srow8) << 4;
  const int vrow4 = lane >> 4;

  auto stage = [&](int buf, int kt) {
    const int kbase = kt * 128;
#pragma unroll
    for (int i = 0; i < 4; ++i) {
      const int ck = wid + i * 4;
      const int krow = ck * 8 + srow8;
      gload_lds16((const char*)(kg0 + (size_t)(kbase + krow) * NQKV) + skk,
                  Ks[buf] + ck * 1024);
      const int cv = wid + i * 4;
      const int vr = cv * 4 + vrow4;
      const int ss = (lane & 15) ^ (vr & 15);
      gload_lds16((const char*)(vg0 + (size_t)vr * S + kbase + ss * 8),
                  Vs[buf] + cv * 1024);
    }
  };

  f32x16 o[2] = {};
  float lpart = 0.f;

  const int rswz8 = (l5 & 7) << 4;
  const int rswz16 = (l5 & 15) << 4;

  stage(0, 0);

  int cur = 0;
  for (int kt = 0; kt < NT; ++kt) {
    asm volatile("s_waitcnt vmcnt(0)" ::: "memory");
    __builtin_amdgcn_s_barrier();
    __builtin_amdgcn_sched_barrier(0);
    if (kt + 1 < NT) stage(cur ^ 1, kt + 1);

    const int kbase = kt * 128;

    f32x16 sc[4];
    __builtin_amdgcn_s_setprio(1);
#pragma unroll
    for (int kh = 0; kh < 4; ++kh) {
      f32x16 t2 = {};
#pragma unroll
      for (int ks = 0; ks < 4; ++ks) {
        const short8 kf = *(const short8*)(Ks[cur] + (kh * 32 + l5) * 128 +
                                           ((ks * 32 + hw * 16) ^ rswz8));
        t2 = __builtin_amdgcn_mfma_f32_32x32x16_bf16(kf, qf[ks], t2, 0, 0, 0);
      }
      sc[kh] = t2;
    }
    __builtin_amdgcn_s_setprio(0);

    short8 vf[2][8];
#pragma unroll
    for (int dh = 0; dh < 2; ++dh)
#pragma unroll
      for (int s = 0; s < 8; ++s)
        vf[dh][s] = *(const short8*)(Vs[cur] + (dh * 32 + l5) * 256 +
                                     ((s * 32 + hw * 16) ^ rswz16));

    if (bflags[2 * kt] | bflags[2 * kt + 1]) {
#pragma unroll
      for (int kh = 0; kh < 4; ++kh)
#pragma unroll
        for (int m = 0; m < 4; ++m) {
          const f32x4 a4 = *(const f32x4*)(maskadd + b * S + kbase + kh * 32 + m * 8 + hw * 4);
#pragma unroll
          for (int r = 0; r < 4; ++r)
            sc[kh][m * 4 + r] += a4[r];
        }
    }

    float ps = 0.f;
#pragma unroll
    for (int kh = 0; kh < 4; ++kh) {
#pragma unroll
      for (int r = 0; r < 16; ++r)
        sc[kh][r] = fexp2(sc[kh][r]);
#pragma unroll
      for (int m = 0; m < 4; ++m)
        ps += (sc[kh][4 * m] + sc[kh][4 * m + 1]) + (sc[kh][4 * m + 2] + sc[kh][4 * m + 3]);

      const unsigned c00 = cvt_pk_bf16(sc[kh][0], sc[kh][1]);
      const unsigned c01 = cvt_pk_bf16(sc[kh][2], sc[kh][3]);
      const unsigned c10 = cvt_pk_bf16(sc[kh][4], sc[kh][5]);
      const unsigned c11 = cvt_pk_bf16(sc[kh][6], sc[kh][7]);
      const unsigned c20 = cvt_pk_bf16(sc[kh][8], sc[kh][9]);
      const unsigned c21 = cvt_pk_bf16(sc[kh][10], sc[kh][11]);
      const unsigned c30 = cvt_pk_bf16(sc[kh][12], sc[kh][13]);
      const unsigned c31 = cvt_pk_bf16(sc[kh][14], sc[kh][15]);
      const uint2v r0 = permswap(c00, c10);
      const uint2v r1 = permswap(c01, c11);
      const uint2v r2 = permswap(c20, c30);
      const uint2v r3 = permswap(c21, c31);
      uint4v p0, p1;
      p0[0] = r0[0]; p0[2] = r0[1]; p0[1] = r1[0]; p0[3] = r1[1];
      p1[0] = r2[0]; p1[2] = r2[1]; p1[1] = r3[0]; p1[3] = r3[1];
      const short8 pb0 = __builtin_bit_cast(short8, p0);
      const short8 pb1 = __builtin_bit_cast(short8, p1);

      __builtin_amdgcn_s_setprio(1);
#pragma unroll
      for (int dh = 0; dh < 2; ++dh) {
        o[dh] = __builtin_amdgcn_mfma_f32_32x32x16_bf16(vf[dh][2 * kh], pb0, o[dh], 0, 0, 0);
        o[dh] = __builtin_amdgcn_mfma_f32_32x32x16_bf16(vf[dh][2 * kh + 1], pb1, o[dh], 0, 0, 0);
      }
      __builtin_amdgcn_s_setprio(0);
    }
    lpart += ps;

    cur ^= 1;
  }

  const float ls = lpart + __shfl_xor(lpart, 32);
  const float inv = 1.0f / ls;
  unsigned short* orow = attn + (size_t)(b * S + q) * D + h * DK;
#pragma unroll
  for (int dh = 0; dh < 2; ++dh)
#pragma unroll
    for (int m = 0; m < 4; ++m) {
      const int d = dh * 32 + m * 8 + hw * 4;
      uint2 w;
      w.x = cvt_pk_bf16(o[dh][4 * m + 0] * inv, o[dh][4 * m + 1] * inv);
      w.y = cvt_pk_bf16(o[dh][4 * m + 2] * inv, o[dh][4 * m + 3] * inv);
      *(uint2*)(orow + d) = w;
    }
}

extern "C" void kernel_launch(void* const* d_in, const int* in_sizes, int n_in,
                              void* d_out, int out_size, void* d_ws, size_t ws_size,
                              hipStream_t stream) {
  const float* x = (const float*)d_in[0];
  const int* mask = (const int*)d_in[1];
  const float* W_qkv = (const float*)d_in[2];
  const float* b_qkv = (const float*)d_in[3];
  const float* W_out = (const float*)d_in[4];
  const float* b_out = (const float*)d_in[5];
  float* out = (float*)d_out;

  char* ws = (char*)d_ws;
  unsigned short* x_bf   = (unsigned short*)(ws);                          //  0..8 MB
  unsigned short* wqkv_t = (unsigned short*)(ws + (size_t)(8 << 20));      //  8..14 MB
  unsigned short* wout_t = (unsigned short*)(ws + (size_t)(14 << 20));     // 14..16 MB
  unsigned short* qkv    = (unsigned short*)(ws + (size_t)(16 << 20));     // 16..40 MB
  unsigned short* vtr    = (unsigned short*)(ws + (size_t)(40 << 20));     // 40..48 MB
  unsigned short* attn   = (unsigned short*)(ws + (size_t)(48 << 20));     // 48..56 MB
  float*          madd   = (float*)(ws + (size_t)(56 << 20));              // 16 KB
  unsigned char*  tflags = (unsigned char*)(ws + (size_t)(56 << 20) + 16384);  // 64 B

  k_prep<<<NB_CVT + NB_WQKV + NB_WOUT + NB_MASK, 256, 0, stream>>>(
      x, x_bf, W_qkv, wqkv_t, W_out, wout_t, mask, madd, tflags);
  k_gemm_qkv<<<(TOK / 128) * (NQKV / 128), 256, 0, stream>>>(x_bf, wqkv_t, b_qkv, qkv, vtr);
  k_attn<<<BATCH * H * (S / 128), 256, 0, stream>>>(qkv, vtr, madd, tflags, attn);
  k_gemm_out<<<(TOK / 64) * (D / 128), 256, 0, stream>>>(attn, wout_t, b_out, out, TOK, D, D);
}